// Round 1
// baseline (157.314 us; speedup 1.0000x reference)
//
#include <hip/hip_runtime.h>

#define N_NODES 50000
#define K 32
#define F 128
#define NEG_SLOPE 0.01f
#define NODES_PER_BLOCK 8

__global__ __launch_bounds__(256) void gat_symmetry_reduce_kernel(
    const float* __restrict__ a1_node,   // (N,1)
    const float* __restrict__ a2_node,   // (N,1)
    const float* __restrict__ a1_mail,   // (N,K,1)
    const float* __restrict__ a2_mail,   // (N,K,1)
    const float* __restrict__ ft,        // (N,K,F)
    float* __restrict__ out)             // (N,F)
{
    const int tid = threadIdx.x;
    const int grp = tid >> 5;        // 0..7  (node within block)
    const int lk  = tid & 31;        // lane within 32-lane group: k index AND f-chunk index
    const int n   = blockIdx.x * NODES_PER_BLOCK + grp;
    if (n >= N_NODES) return;

    // ---- logits: lrelu(a1n + a2m + 2*(a2n + a1m)) for k = lk ----
    const float a1n = a1_node[n];
    const float a2n = a2_node[n];
    const float m1  = a1_mail[(size_t)n * K + lk];
    const float m2  = a2_mail[(size_t)n * K + lk];
    const float x   = a1n + m2 + 2.0f * (a2n + m1);
    const float logit = (x >= 0.0f) ? x : NEG_SLOPE * x;

    // ---- softmax over the 32-lane group ----
    float m = logit;
    #pragma unroll
    for (int off = 16; off >= 1; off >>= 1)
        m = fmaxf(m, __shfl_xor(m, off, 32));
    const float p = __expf(logit - m);
    float s = p;
    #pragma unroll
    for (int off = 16; off >= 1; off >>= 1)
        s += __shfl_xor(s, off, 32);
    const float e = p / s;   // lane lk holds e[n, lk]

    // ---- weighted sum over K: lane lk owns float4 chunk lk of F (F/4 = 32 chunks) ----
    const float4* __restrict__ ft4 = reinterpret_cast<const float4*>(ft + (size_t)n * K * F);
    float4 acc = make_float4(0.0f, 0.0f, 0.0f, 0.0f);
    #pragma unroll 8
    for (int k = 0; k < K; ++k) {
        const float w = __shfl(e, k, 32);      // broadcast e[n,k] across the group
        const float4 v = ft4[k * (F / 4) + lk];
        acc.x += w * v.x;
        acc.y += w * v.y;
        acc.z += w * v.z;
        acc.w += w * v.w;
    }
    reinterpret_cast<float4*>(out + (size_t)n * F)[lk] = acc;
}

extern "C" void kernel_launch(void* const* d_in, const int* in_sizes, int n_in,
                              void* d_out, int out_size, void* d_ws, size_t ws_size,
                              hipStream_t stream) {
    const float* a1_node = (const float*)d_in[0];
    const float* a2_node = (const float*)d_in[1];
    const float* a1_mail = (const float*)d_in[2];
    const float* a2_mail = (const float*)d_in[3];
    const float* ft      = (const float*)d_in[4];
    float* out = (float*)d_out;

    const int blocks = (N_NODES + NODES_PER_BLOCK - 1) / NODES_PER_BLOCK;  // 6250
    gat_symmetry_reduce_kernel<<<blocks, 256, 0, stream>>>(
        a1_node, a2_node, a1_mail, a2_mail, ft, out);
}

// Round 3
// 140.337 us; speedup vs baseline: 1.1210x; 1.1210x over previous
//
#include <hip/hip_runtime.h>

#define N_NODES 50000
#define K 32
#define F 128
#define NEG_SLOPE 0.01f
#define NODES_PER_BLOCK 8

typedef float f32x4 __attribute__((ext_vector_type(4)));

__global__ __launch_bounds__(256) void gat_symmetry_reduce_kernel(
    const float* __restrict__ a1_node,   // (N,1)
    const float* __restrict__ a2_node,   // (N,1)
    const float* __restrict__ a1_mail,   // (N,K,1)
    const float* __restrict__ a2_mail,   // (N,K,1)
    const float* __restrict__ ft,        // (N,K,F)
    float* __restrict__ out)             // (N,F)
{
    const int tid = threadIdx.x;
    const int grp = tid >> 5;        // 0..7  (node within block)
    const int lk  = tid & 31;        // lane within 32-lane group: k index AND f-chunk index
    const int n   = blockIdx.x * NODES_PER_BLOCK + grp;
    if (n >= N_NODES) return;

    // ---- logits: lrelu(a1n + a2m + 2*(a2n + a1m)) for k = lk ----
    const float a1n = a1_node[n];
    const float a2n = a2_node[n];
    const float m1  = a1_mail[(size_t)n * K + lk];
    const float m2  = a2_mail[(size_t)n * K + lk];
    const float x   = a1n + m2 + 2.0f * (a2n + m1);
    const float logit = (x >= 0.0f) ? x : NEG_SLOPE * x;

    // ---- softmax over the 32-lane group ----
    float m = logit;
    #pragma unroll
    for (int off = 16; off >= 1; off >>= 1)
        m = fmaxf(m, __shfl_xor(m, off, 32));
    const float p = __expf(logit - m);
    float s = p;
    #pragma unroll
    for (int off = 16; off >= 1; off >>= 1)
        s += __shfl_xor(s, off, 32);
    const float e = p / s;   // lane lk holds e[n, lk]

    // ---- weighted sum over K: lane lk owns float4 chunk lk of F (F/4 = 32 chunks) ----
    // ft is streamed exactly once -> non-temporal loads (skip cache allocation).
    const f32x4* __restrict__ ft4 = reinterpret_cast<const f32x4*>(ft + (size_t)n * K * F);
    f32x4 acc = {0.0f, 0.0f, 0.0f, 0.0f};
    #pragma unroll 8
    for (int k = 0; k < K; ++k) {
        const float w = __shfl(e, k, 32);      // broadcast e[n,k] across the group
        const f32x4 v = __builtin_nontemporal_load(&ft4[k * (F / 4) + lk]);
        acc += w * v;
    }
    f32x4* __restrict__ out4 = reinterpret_cast<f32x4*>(out + (size_t)n * F);
    __builtin_nontemporal_store(acc, &out4[lk]);
}

extern "C" void kernel_launch(void* const* d_in, const int* in_sizes, int n_in,
                              void* d_out, int out_size, void* d_ws, size_t ws_size,
                              hipStream_t stream) {
    const float* a1_node = (const float*)d_in[0];
    const float* a2_node = (const float*)d_in[1];
    const float* a1_mail = (const float*)d_in[2];
    const float* a2_mail = (const float*)d_in[3];
    const float* ft      = (const float*)d_in[4];
    float* out = (float*)d_out;

    const int blocks = (N_NODES + NODES_PER_BLOCK - 1) / NODES_PER_BLOCK;  // 6250
    gat_symmetry_reduce_kernel<<<blocks, 256, 0, stream>>>(
        a1_node, a2_node, a1_mail, a2_mail, ft, out);
}